// Round 6
// baseline (213.852 us; speedup 1.0000x reference)
//
#include <hip/hip_runtime.h>
#include <stdint.h>

#define BSZ 16
#define TT  2048
#define NSEM 2048
#define DIM 128
#define ORS 1024          // shorts per output row (512 floats)
#define PSTR 68           // pbuf row stride in shorts

typedef __attribute__((ext_vector_type(8))) short short8;
typedef __attribute__((ext_vector_type(4))) float floatx4;

__device__ __forceinline__ unsigned short f2bf(float f){       // RNE
  unsigned u = __float_as_uint(f);
  return (unsigned short)((u + 0x7fffu + ((u >> 16) & 1u)) >> 16);
}
__device__ __forceinline__ void ld8f(const float* p, float* v){
  floatx4 a = *(const floatx4*)p;
  floatx4 b = *(const floatx4*)(p + 4);
  v[0]=a[0]; v[1]=a[1]; v[2]=a[2]; v[3]=a[3];
  v[4]=b[0]; v[5]=b[1]; v[6]=b[2]; v[7]=b[3];
}
// async global->LDS: 64 lanes x 16B; LDS dest is wave-uniform base + lane*16.
__device__ __forceinline__ void gload_lds16(const unsigned short* g, unsigned short* l){
  __builtin_amdgcn_global_load_lds((const __attribute__((address_space(1))) void*)g,
                                   (__attribute__((address_space(3))) void*)l, 16, 0, 0);
}

// Staging layout (in out buffer, shorts [512,1024) of rows b*TT + c, 1KB each):
//   KST chunk cK = nblk*4 + kc            (cK in [0,512))   : [quad][l15][8] = K[nblk*16+l15][kc*32+quad*8+j]
//   VST chunk cV = 512 + ntile*16 + kt*8 + dc (cV in [512,1024)) : [quad][l15][8] = V[ntile*64+kt*32+quad*8+j][dc*16+l15]
// One chunk == one global_load_lds instruction == one conflict-free ds_read_b128 per wave.

// ---------------- kernel 1: prep ----------------
// grid 512 (b = bx>>5, n0 = (bx&31)*64), 256 thr.
__global__ __launch_bounds__(256) void prep_kernel(const float* __restrict__ sem,
                                                   const float* __restrict__ W,
                                                   float* __restrict__ colB,
                                                   unsigned short* __restrict__ outw){
  __shared__ unsigned short tile[DIM * 72];        // [d][n] bf16, stride 72 (144B, 16B-mult)
  const int tid = threadIdx.x;
  const int b  = blockIdx.x >> 5;
  const int n0 = (blockIdx.x & 31) * 64;

  // phase 1: row r (64 rows), col chunk c (32 cols)
  const int r = tid >> 2, cc = tid & 3, c = cc * 32;
  const float* src = sem + ((size_t)(b * NSEM + n0 + r)) * DIM + c;
  float v[32];
  ld8f(src, v); ld8f(src + 8, v + 8); ld8f(src + 16, v + 16); ld8f(src + 24, v + 24);
  alignas(16) unsigned short bf[32];
  float cpart = 0.f;
  #pragma unroll
  for (int j = 0; j < 32; ++j){
    bf[j] = f2bf(v[j]);
    cpart += v[j] * W[DIM + c + j];                // w2 dot partial
  }
  // KST write: chunk (nblk, kc=cc), row l15 = r&15. 4 x 16B at stride 256B.
  {
    const int nblk = (n0 >> 4) + (r >> 4);
    const int l15r = r & 15;
    unsigned short* base = outw + ((size_t)(b * TT + nblk * 4 + cc)) * ORS + 512;
    const uint4* s4 = (const uint4*)bf;
    #pragma unroll
    for (int q = 0; q < 4; ++q)
      *(uint4*)(base + q * 128 + l15r * 8) = s4[q];
  }
  // LDS transpose stage
  #pragma unroll
  for (int j = 0; j < 32; ++j) tile[(c + j) * 72 + r] = bf[j];
  // colB reduce over the 4 col-chunks (lanes differing in bits 0..1)
  cpart += __shfl_xor(cpart, 1);
  cpart += __shfl_xor(cpart, 2);
  if (cc == 0) colB[b * NSEM + n0 + r] = cpart;
  __syncthreads();

  // phase 2: VST write. kt = tid>>7 (2), dc = (tid>>4)&7 (8), l15 = tid&15.
  {
    const int kt = tid >> 7, dc = (tid >> 4) & 7, l15 = tid & 15;
    const int d = dc * 16 + l15;
    const int ntile = n0 >> 6;
    unsigned short* base = outw + ((size_t)(b * TT + 512 + ntile * 16 + kt * 8 + dc)) * ORS + 512;
    #pragma unroll
    for (int q = 0; q < 4; ++q){
      uint4 tv = *(const uint4*)&tile[d * 72 + kt * 32 + q * 8];
      *(uint4*)(base + q * 128 + l15 * 8) = tv;
    }
  }
}

// ---------------- kernel 2: flash attention, 32 t-rows/wave, LDS-staged K/V ----------------
// grid 256 (b = bx>>4, 128-row t-block), 256 thr = 4 waves; wave wv owns rows
// t0w..t0w+31 as two 16-row groups (g=0,1). Each K/V fragment read from LDS feeds
// BOTH groups' MFMAs -> LDS read bytes per unit work halved vs 16t/wave.
// 1 block/CU (LDS 83KB); __launch_bounds__(256,1) -> no register pressure.
__global__ __launch_bounds__(256, 1) void flash_kernel(const float* __restrict__ aud,
                                                    const float* __restrict__ W,
                                                    const float* __restrict__ colB,
                                                    float* __restrict__ m_ws,
                                                    float* __restrict__ outf,
                                                    const unsigned short* __restrict__ outw){
  __shared__ alignas(16) unsigned short kvt[2][32][512];      // 2 bufs x 32 chunks x 1KB = 64 KB
  __shared__ alignas(16) unsigned short pbuf[4][32 * PSTR];   // per-wave P staging (32 rows), 17408 B

  const int tid  = threadIdx.x;
  const int wv   = tid >> 6;
  const int lane = tid & 63;
  const int quad = lane >> 4;
  const int l15  = lane & 15;
  const int b    = blockIdx.x >> 4;
  const int t0w  = (blockIdx.x & 15) * 128 + wv * 32;         // this wave's 32 rows

  // per-lane global staging base (shorts [512,1024) of rows b*TT + c)
  const unsigned short* stage = outw + (size_t)b * TT * ORS + 512 + lane * 8;

  // prologue: stage tile 0 (chunks j = wv*8..wv*8+7; j<16 => K, else V)
  #pragma unroll
  for (int jj = 0; jj < 8; ++jj){
    const int j = wv * 8 + jj;
    const int row = (j < 16) ? j : 512 + (j - 16);
    gload_lds16(stage + (size_t)row * ORS, &kvt[0][j][0]);
  }

  // q A-frags (aud*w3 -> bf16) + rowA partial (fp32 dot aud,w1), two 16-row groups
  short8 qf[2][4];
  float rowA[2];
  #pragma unroll
  for (int g = 0; g < 2; ++g){
    const float* audRow = aud + ((size_t)b * TT + t0w + g * 16 + l15) * DIM;
    float rp = 0.f;
    #pragma unroll
    for (int kc = 0; kc < 4; ++kc){
      int d0 = kc * 32 + quad * 8;
      float av[8], w3v[8], w1v[8];
      ld8f(audRow + d0, av);
      ld8f(W + 2 * DIM + d0, w3v);
      ld8f(W + d0, w1v);
      alignas(16) unsigned short tmp[8];
      #pragma unroll
      for (int j = 0; j < 8; ++j){
        tmp[j] = f2bf(av[j] * w3v[j]);
        rp += av[j] * w1v[j];
      }
      qf[g][kc] = *(const short8*)tmp;
    }
    rp += __shfl_xor(rp, 16);
    rp += __shfl_xor(rp, 32);       // full-d dot for row t0w+g*16+l15, replicated
    rowA[g] = rp;
  }

  float m_run[2] = {-1e30f, -1e30f}, l_run[2] = {0.f, 0.f};   // per-lane rows
  floatx4 o[2][8];
  #pragma unroll
  for (int g = 0; g < 2; ++g)
    #pragma unroll
    for (int dc = 0; dc < 8; ++dc)
      #pragma unroll
      for (int r = 0; r < 4; ++r) o[g][dc][r] = 0.f;

  const float* colBb = colB + b * NSEM;
  unsigned short* pb = &pbuf[wv][0];

  __syncthreads();                                  // tile 0 staged (drains vmcnt too)

  for (int it = 0; it < 32; ++it){
    const int n0 = it * 64;
    // ---- prefetch tile it+1 into the other buffer (DMA, no regs) ----
    if (it + 1 < 32){
      #pragma unroll
      for (int jj = 0; jj < 8; ++jj){
        const int j = wv * 8 + jj;
        const int row = (j < 16) ? (it + 1) * 16 + j : 512 + (it + 1) * 16 + (j - 16);
        gload_lds16(stage + (size_t)row * ORS, &kvt[(it + 1) & 1][j][0]);
      }
    }
    const unsigned short* kvb = &kvt[it & 1][0][0] + lane * 8;

    // colB addends: per lane n = n0 + s*16 + quad*4 + r (group-independent)
    floatx4 cbv[4];
    #pragma unroll
    for (int s = 0; s < 4; ++s) cbv[s] = *(const floatx4*)(colBb + n0 + s*16 + quad*4);

    // ---- QK swapped: each K frag read ONCE, used for BOTH t-groups ----
    floatx4 sacc[2][4];
    #pragma unroll
    for (int g = 0; g < 2; ++g)
      #pragma unroll
      for (int s = 0; s < 4; ++s){ sacc[g][s][0]=0.f; sacc[g][s][1]=0.f; sacc[g][s][2]=0.f; sacc[g][s][3]=0.f; }
    #pragma unroll
    for (int s = 0; s < 4; ++s){
      #pragma unroll
      for (int kc = 0; kc < 4; ++kc){
        short8 kf = *(const short8*)(kvb + (s*4 + kc) * 512);
        sacc[0][s] = __builtin_amdgcn_mfma_f32_16x16x32_bf16(kf, qf[0][kc], sacc[0][s], 0, 0, 0);
        sacc[1][s] = __builtin_amdgcn_mfma_f32_16x16x32_bf16(kf, qf[1][kc], sacc[1][s], 0, 0, 0);
      }
    }

    // ---- online softmax, row-local (t = l15 of each group) ----
    float al[2];
    #pragma unroll
    for (int g = 0; g < 2; ++g){
      float v[4][4];
      #pragma unroll
      for (int s = 0; s < 4; ++s)
        #pragma unroll
        for (int r = 0; r < 4; ++r) v[s][r] = sacc[g][s][r] + cbv[s][r];
      float mq[4];
      #pragma unroll
      for (int s = 0; s < 4; ++s)
        mq[s] = fmaxf(fmaxf(v[s][0], v[s][1]), fmaxf(v[s][2], v[s][3]));
      float mx = fmaxf(fmaxf(mq[0], mq[1]), fmaxf(mq[2], mq[3]));
      mx = fmaxf(mx, __shfl_xor(mx, 16));
      mx = fmaxf(mx, __shfl_xor(mx, 32));
      float mnew = fmaxf(m_run[g], mx);
      al[g] = __expf(m_run[g] - mnew);
      m_run[g] = mnew;
      float e[4][4];
      #pragma unroll
      for (int s = 0; s < 4; ++s)
        #pragma unroll
        for (int r = 0; r < 4; ++r) e[s][r] = __expf(v[s][r] - mnew);
      float sq[4];
      #pragma unroll
      for (int s = 0; s < 4; ++s)
        sq[s] = (e[s][0] + e[s][1]) + (e[s][2] + e[s][3]);
      float ps = (sq[0] + sq[1]) + (sq[2] + sq[3]);
      ps += __shfl_xor(ps, 16);
      ps += __shfl_xor(ps, 32);
      l_run[g] = l_run[g] * al[g] + ps;

      // P staging: row t = g*16 + l15, cols n; pack bf16 pairs -> 8 ds_write_b32
      #pragma unroll
      for (int s = 0; s < 4; ++s){
        unsigned u0 = (unsigned)f2bf(e[s][0]) | ((unsigned)f2bf(e[s][1]) << 16);
        unsigned u1 = (unsigned)f2bf(e[s][2]) | ((unsigned)f2bf(e[s][3]) << 16);
        unsigned short* pr = pb + (g*16 + l15) * PSTR + s * 16 + quad * 4;
        *(unsigned*)(pr)     = u0;
        *(unsigned*)(pr + 2) = u1;
      }
    }

    // o-rescale: o[g] rows are t = g*16 + quad*4+r -> alpha from lane quad*4+r
    #pragma unroll
    for (int g = 0; g < 2; ++g){
      float aB[4];
      #pragma unroll
      for (int r = 0; r < 4; ++r) aB[r] = __shfl(al[g], quad*4 + r);
      #pragma unroll
      for (int dc = 0; dc < 8; ++dc)
        #pragma unroll
        for (int r = 0; r < 4; ++r) o[g][dc][r] *= aB[r];
    }

    // wave-local LDS visibility (in-order DS per wave; just drain writes)
    asm volatile("s_waitcnt lgkmcnt(0)" ::: "memory");
    short8 pf[2][2];
    #pragma unroll
    for (int g = 0; g < 2; ++g){
      pf[g][0] = *(const short8*)(pb + (g*16 + l15) * PSTR + quad * 8);
      pf[g][1] = *(const short8*)(pb + (g*16 + l15) * PSTR + 32 + quad * 8);
    }

    // ---- PV: each V frag read ONCE, used for BOTH t-groups ----
    #pragma unroll
    for (int kt = 0; kt < 2; ++kt){
      #pragma unroll
      for (int dc = 0; dc < 8; ++dc){
        short8 vf = *(const short8*)(kvb + (16 + kt*8 + dc) * 512);
        o[0][dc] = __builtin_amdgcn_mfma_f32_16x16x32_bf16(pf[0][kt], vf, o[0][dc], 0, 0, 0);
        o[1][dc] = __builtin_amdgcn_mfma_f32_16x16x32_bf16(pf[1][kt], vf, o[1][dc], 0, 0, 0);
      }
    }

    // tile boundary: drains this wave's prefetch (vmcnt) + syncs buffer swap
    __syncthreads();
  }

  // ---- epilogue: h = O/l -> out seg1 (fp32); m (+rowA) -> ws ----
  #pragma unroll
  for (int g = 0; g < 2; ++g){
    float rl = 1.0f / l_run[g];
    float rB[4];
    #pragma unroll
    for (int r = 0; r < 4; ++r) rB[r] = __shfl(rl, quad*4 + r);
    float* outB = outf + ((size_t)b * TT + t0w + g*16) * 512 + 128;
    #pragma unroll
    for (int dc = 0; dc < 8; ++dc)
      #pragma unroll
      for (int r = 0; r < 4; ++r)
        outB[(size_t)(quad*4 + r) * 512 + dc*16 + l15] = o[g][dc][r] * rB[r];
    if (quad == 0)
      m_ws[(size_t)b * TT + t0w + g*16 + l15] = m_run[g] + rowA[g];
  }
}

// ---------------- kernel 3a: per-chunk max of m ----------------
__global__ __launch_bounds__(256) void bw1_kernel(const float* __restrict__ m_ws,
                                                  float* __restrict__ pmax){
  __shared__ float sA[4];
  const int b = blockIdx.x >> 3, ch = blockIdx.x & 7, tid = threadIdx.x;
  float v = m_ws[(size_t)b * TT + ch * 256 + tid];
  #pragma unroll
  for (int off = 1; off < 64; off <<= 1) v = fmaxf(v, __shfl_xor(v, off));
  if ((tid & 63) == 0) sA[tid >> 6] = v;
  __syncthreads();
  if (tid == 0)
    pmax[blockIdx.x] = fmaxf(fmaxf(sA[0], sA[1]), fmaxf(sA[2], sA[3]));
}

// ---------------- kernel 3b: partial exp-sum + partial a2 ----------------
__global__ __launch_bounds__(256) void bw2_kernel(const float* __restrict__ aud,
                                                  const float* __restrict__ m_ws,
                                                  const float* __restrict__ pmax,
                                                  float* __restrict__ gpart,
                                                  float* __restrict__ part){
  __shared__ float wbuf[256];
  __shared__ float red[16 * 128];
  __shared__ float gs4[4];
  const int b = blockIdx.x >> 3, ch = blockIdx.x & 7, tid = threadIdx.x;

  float gmax = pmax[b * 8];
  #pragma unroll
  for (int i = 1; i < 8; ++i) gmax = fmaxf(gmax, pmax[b * 8 + i]);

  float w = __expf(m_ws[(size_t)b * TT + ch * 256 + tid] - gmax);
  wbuf[tid] = w;
  float sm = w;
  #pragma unroll
  for (int off = 1; off < 64; off <<= 1) sm += __shfl_xor(sm, off);
  if ((tid & 63) == 0) gs4[tid >> 6] = sm;
  __syncthreads();
  if (tid == 0) gpart[blockIdx.x] = (gs4[0] + gs4[1]) + (gs4[2] + gs4[3]);

  const int dg = tid & 15, q = tid >> 4;
  float acc[8] = {0,0,0,0,0,0,0,0};
  const float* ab = aud + ((size_t)b * TT + ch * 256 + q * 16) * DIM + dg * 8;
  for (int i = 0; i < 16; ++i){
    float av[8];
    ld8f(ab + (size_t)i * DIM, av);
    float wt = wbuf[q * 16 + i];
    #pragma unroll
    for (int j = 0; j < 8; ++j) acc[j] += wt * av[j];
  }
  #pragma unroll
  for (int j = 0; j < 8; ++j) red[q * 128 + dg * 8 + j] = acc[j];
  __syncthreads();
  if (tid < 128){
    float s = 0.f;
    #pragma unroll
    for (int q2 = 0; q2 < 16; ++q2) s += red[q2 * 128 + tid];
    part[(size_t)blockIdx.x * 128 + tid] = s;
  }
}

// ---------------- kernel 3c: combine partials -> normalized a2 ----------------
__global__ __launch_bounds__(128) void bw3_kernel(const float* __restrict__ gpart,
                                                  const float* __restrict__ part,
                                                  float* __restrict__ a2_ws){
  const int b = blockIdx.x, d = threadIdx.x;
  float s = 0.f, g = 0.f;
  #pragma unroll
  for (int ch = 0; ch < 8; ++ch){
    s += part[(size_t)(b * 8 + ch) * 128 + d];
    g += gpart[b * 8 + ch];
  }
  a2_ws[b * DIM + d] = s / g;
}

// ---------------- kernel 4: read seg1 (h), write seg0/2/3 ----------------
__global__ __launch_bounds__(256) void epi_kernel(const float* __restrict__ aud,
                                                  const float* __restrict__ a2_ws,
                                                  float* __restrict__ out){
  int id = blockIdx.x * 256 + threadIdx.x;        // BSZ*TT*16
  int c = id & 15;
  int t = (id >> 4) & (TT - 1);
  int b = id >> 15;
  size_t row = (size_t)b * TT + t;

  float av[8], gv[8], hv[8];
  ld8f(aud + row * DIM + c * 8, av);
  ld8f(a2_ws + b * DIM + c * 8, gv);
  ld8f(out + row * 512 + 128 + c * 8, hv);        // h (seg1)

  floatx4 o0a, o0b, o2a, o2b, o3a, o3b;
  #pragma unroll
  for (int j = 0; j < 4; ++j){
    o0a[j] = av[j];           o0b[j] = av[4+j];
    o2a[j] = av[j]*hv[j];     o2b[j] = av[4+j]*hv[4+j];
    o3a[j] = av[j]*gv[j];     o3b[j] = av[4+j]*gv[4+j];
  }
  float* ob = out + row * 512 + c * 8;
  *(floatx4*)(ob)       = o0a;  *(floatx4*)(ob + 4)   = o0b;   // seg0: aud
  *(floatx4*)(ob + 256) = o2a;  *(floatx4*)(ob + 260) = o2b;   // seg2: aud*h
  *(floatx4*)(ob + 384) = o3a;  *(floatx4*)(ob + 388) = o3b;   // seg3: aud*a2
}

extern "C" void kernel_launch(void* const* d_in, const int* in_sizes, int n_in,
                              void* d_out, int out_size, void* d_ws, size_t ws_size,
                              hipStream_t stream){
  const float* aud = (const float*)d_in[0];   // fp32 inputs (verified round 4)
  const float* sem = (const float*)d_in[1];
  const float* W   = (const float*)d_in[2];
  // d_in[3] (bias) cancels in both softmaxes.
  float* out = (float*)d_out;                 // fp32 output (verified round 4)
  unsigned short* outw = (unsigned short*)d_out;

  // ws: ~329 KB
  float* ws    = (float*)d_ws;
  float* m_ws  = ws;                                   // 32768 f (128 KB)
  float* colB  = m_ws + (size_t)BSZ * TT;              // 32768 f (128 KB)
  float* a2_ws = colB + (size_t)BSZ * NSEM;            // 2048 f  (8 KB)
  float* pmax  = a2_ws + BSZ * DIM;                    // 128 f
  float* gpart = pmax + 128;                           // 128 f
  float* part  = gpart + 128;                          // 16384 f (64 KB)

  prep_kernel <<<512, 256, 0, stream>>>(sem, W, colB, outw);
  flash_kernel<<<256, 256, 0, stream>>>(aud, W, colB, m_ws, out, outw);
  bw1_kernel  <<<128, 256, 0, stream>>>(m_ws, pmax);
  bw2_kernel  <<<128, 256, 0, stream>>>(aud, m_ws, pmax, gpart, part);
  bw3_kernel  <<<BSZ, 128, 0, stream>>>(gpart, part, a2_ws);
  epi_kernel  <<<(BSZ * TT * 16) / 256, 256, 0, stream>>>(aud, a2_ws, out);
}

// Round 7
// 197.262 us; speedup vs baseline: 1.0841x; 1.0841x over previous
//
#include <hip/hip_runtime.h>
#include <stdint.h>

#define BSZ 16
#define TT  2048
#define NSEM 2048
#define DIM 128
#define ORS 1024          // shorts per output row (512 floats)
#define PSTR 68           // pbuf row stride in shorts

typedef __attribute__((ext_vector_type(8))) short short8;
typedef __attribute__((ext_vector_type(4))) float floatx4;

__device__ __forceinline__ unsigned short f2bf(float f){       // RNE
  unsigned u = __float_as_uint(f);
  return (unsigned short)((u + 0x7fffu + ((u >> 16) & 1u)) >> 16);
}
__device__ __forceinline__ void ld8f(const float* p, float* v){
  floatx4 a = *(const floatx4*)p;
  floatx4 b = *(const floatx4*)(p + 4);
  v[0]=a[0]; v[1]=a[1]; v[2]=a[2]; v[3]=a[3];
  v[4]=b[0]; v[5]=b[1]; v[6]=b[2]; v[7]=b[3];
}
// async global->LDS: 64 lanes x 16B; LDS dest is wave-uniform base + lane*16.
__device__ __forceinline__ void gload_lds16(const unsigned short* g, unsigned short* l){
  __builtin_amdgcn_global_load_lds((const __attribute__((address_space(1))) void*)g,
                                   (__attribute__((address_space(3))) void*)l, 16, 0, 0);
}

// Staging layout (in out buffer, shorts [512,1024) of rows b*TT + c, 1KB each):
//   KST chunk cK = nblk*4 + kc            (cK in [0,512))   : [quad][l15][8] = K[nblk*16+l15][kc*32+quad*8+j]
//   VST chunk cV = 512 + ntile*16 + kt*8 + dc (cV in [512,1024)) : [quad][l15][8] = V[ntile*64+kt*32+quad*8+j][dc*16+l15]
// One chunk == one coalesced 1KB wave access (16B/lane).

// ---------------- kernel 1: prep ----------------
// grid 512 (b = bx>>5, n0 = (bx&31)*64), 256 thr.
__global__ __launch_bounds__(256) void prep_kernel(const float* __restrict__ sem,
                                                   const float* __restrict__ W,
                                                   float* __restrict__ colB,
                                                   unsigned short* __restrict__ outw){
  __shared__ unsigned short tile[DIM * 72];        // [d][n] bf16, stride 72 (144B, 16B-mult)
  const int tid = threadIdx.x;
  const int b  = blockIdx.x >> 5;
  const int n0 = (blockIdx.x & 31) * 64;

  // phase 1: row r (64 rows), col chunk c (32 cols)
  const int r = tid >> 2, cc = tid & 3, c = cc * 32;
  const float* src = sem + ((size_t)(b * NSEM + n0 + r)) * DIM + c;
  float v[32];
  ld8f(src, v); ld8f(src + 8, v + 8); ld8f(src + 16, v + 16); ld8f(src + 24, v + 24);
  alignas(16) unsigned short bf[32];
  float cpart = 0.f;
  #pragma unroll
  for (int j = 0; j < 32; ++j){
    bf[j] = f2bf(v[j]);
    cpart += v[j] * W[DIM + c + j];                // w2 dot partial
  }
  // KST write: chunk (nblk, kc=cc), row l15 = r&15. 4 x 16B at stride 256B.
  {
    const int nblk = (n0 >> 4) + (r >> 4);
    const int l15r = r & 15;
    unsigned short* base = outw + ((size_t)(b * TT + nblk * 4 + cc)) * ORS + 512;
    const uint4* s4 = (const uint4*)bf;
    #pragma unroll
    for (int q = 0; q < 4; ++q)
      *(uint4*)(base + q * 128 + l15r * 8) = s4[q];
  }
  // LDS transpose stage
  #pragma unroll
  for (int j = 0; j < 32; ++j) tile[(c + j) * 72 + r] = bf[j];
  // colB reduce over the 4 col-chunks (lanes differing in bits 0..1)
  cpart += __shfl_xor(cpart, 1);
  cpart += __shfl_xor(cpart, 2);
  if (cc == 0) colB[b * NSEM + n0 + r] = cpart;
  __syncthreads();

  // phase 2: VST write. kt = tid>>7 (2), dc = (tid>>4)&7 (8), l15 = tid&15.
  {
    const int kt = tid >> 7, dc = (tid >> 4) & 7, l15 = tid & 15;
    const int d = dc * 16 + l15;
    const int ntile = n0 >> 6;
    unsigned short* base = outw + ((size_t)(b * TT + 512 + ntile * 16 + kt * 8 + dc)) * ORS + 512;
    #pragma unroll
    for (int q = 0; q < 4; ++q){
      uint4 tv = *(const uint4*)&tile[d * 72 + kt * 32 + q * 8];
      *(uint4*)(base + q * 128 + l15 * 8) = tv;
    }
  }
}

// ---------------- kernel 2: flash attention ----------------
// grid 512 (b = bx>>5, 64-row t-block), 256 thr = 4 waves; wave wv owns 16 t-rows.
// K: LDS-staged (double-buffered 16KB tiles via global_load_lds).
// V: loaded DIRECT from global (L2/L3-resident coalesced VST chunks) into regs at iter
//    top -> consumed at PV (full-iteration latency window); halves DS-pipe traffic.
// Swapped QK (mfma(K,Q)) -> row-local softmax; defer-max (THR=8) skips o-rescale.
__global__ __launch_bounds__(256, 2) void flash_kernel(const float* __restrict__ aud,
                                                    const float* __restrict__ W,
                                                    const float* __restrict__ colB,
                                                    float* __restrict__ m_ws,
                                                    float* __restrict__ outf,
                                                    const unsigned short* __restrict__ outw){
  __shared__ alignas(16) unsigned short kvt[2][16][512];      // 2 bufs x 16 K-chunks x 1KB = 32 KB
  __shared__ alignas(16) unsigned short pbuf[4][16 * PSTR];   // per-wave P staging, 8704 B

  const int tid  = threadIdx.x;
  const int wv   = tid >> 6;
  const int lane = tid & 63;
  const int quad = lane >> 4;
  const int l15  = lane & 15;
  const int b    = blockIdx.x >> 5;
  const int t0w  = (blockIdx.x & 31) * 64 + wv * 16;          // this wave's 16 rows

  // per-lane global staging base (shorts [512,1024) of rows b*TT + c)
  const unsigned short* stage = outw + (size_t)b * TT * ORS + 512 + lane * 8;

  // prologue: stage K tile 0 (chunks j = wv*4..wv*4+3; global row = j)
  #pragma unroll
  for (int jj = 0; jj < 4; ++jj){
    const int j = wv * 4 + jj;
    gload_lds16(stage + (size_t)j * ORS, &kvt[0][j][0]);
  }

  // q A-frags (aud*w3 -> bf16) + rowA partial (fp32 dot aud,w1)
  const float* audRow = aud + ((size_t)b * TT + t0w + l15) * DIM;
  short8 qf[4];
  float rowA_part = 0.f;
  #pragma unroll
  for (int kc = 0; kc < 4; ++kc){
    int d0 = kc * 32 + quad * 8;
    float av[8], w3v[8], w1v[8];
    ld8f(audRow + d0, av);
    ld8f(W + 2 * DIM + d0, w3v);
    ld8f(W + d0, w1v);
    alignas(16) unsigned short tmp[8];
    #pragma unroll
    for (int j = 0; j < 8; ++j){
      tmp[j] = f2bf(av[j] * w3v[j]);
      rowA_part += av[j] * w1v[j];
    }
    qf[kc] = *(const short8*)tmp;
  }
  rowA_part += __shfl_xor(rowA_part, 16);
  rowA_part += __shfl_xor(rowA_part, 32);   // full-d dot for row t0w + l15, replicated

  float m_run = -1e30f, l_run = 0.f;        // per-lane: row t = t0w + l15
  float m_true = -1e30f;                    // exact running max (defer-max keeps m_run stale)
  floatx4 o[8];
  #pragma unroll
  for (int dc = 0; dc < 8; ++dc){
    #pragma unroll
    for (int r = 0; r < 4; ++r) o[dc][r] = 0.f;
  }

  const float* colBb = colB + b * NSEM;
  unsigned short* pb = &pbuf[wv][0];

  __syncthreads();                                  // K tile 0 staged

  for (int it = 0; it < 32; ++it){
    const int n0 = it * 64;

    // ---- V frags: direct global loads (issued FIRST so their waitcnt doesn't drain DMAs) ----
    const int cV = 512 + it * 16;
    short8 vf[16];
    #pragma unroll
    for (int i = 0; i < 16; ++i) vf[i] = *(const short8*)(stage + (size_t)(cV + i) * ORS);

    // ---- prefetch K tile it+1 (DMA, no regs) ----
    if (it + 1 < 32){
      #pragma unroll
      for (int jj = 0; jj < 4; ++jj){
        const int j = wv * 4 + jj;
        gload_lds16(stage + (size_t)((it + 1) * 16 + j) * ORS, &kvt[(it + 1) & 1][j][0]);
      }
    }
    __builtin_amdgcn_sched_barrier(0);      // pin: all VMEM issued before compute

    const unsigned short* kvb = &kvt[it & 1][0][0] + lane * 8;

    // colB addends: per lane n = n0 + s*16 + quad*4 + r
    floatx4 cbv[4];
    #pragma unroll
    for (int s = 0; s < 4; ++s) cbv[s] = *(const floatx4*)(colBb + n0 + s*16 + quad*4);

    // ---- QK swapped: sacc[s] = K_frag x Q -> S[n=quad*4+r][t=l15] ----
    floatx4 sacc[4];
    #pragma unroll
    for (int s = 0; s < 4; ++s){ sacc[s][0]=0.f; sacc[s][1]=0.f; sacc[s][2]=0.f; sacc[s][3]=0.f; }
    #pragma unroll
    for (int s = 0; s < 4; ++s){
      #pragma unroll
      for (int kc = 0; kc < 4; ++kc){
        short8 kf = *(const short8*)(kvb + (s*4 + kc) * 512);
        sacc[s] = __builtin_amdgcn_mfma_f32_16x16x32_bf16(kf, qf[kc], sacc[s], 0, 0, 0);
      }
    }

    // ---- online softmax, row-local (t = l15), defer-max THR=8 ----
    float v[4][4];
    #pragma unroll
    for (int s = 0; s < 4; ++s){
      #pragma unroll
      for (int r = 0; r < 4; ++r) v[s][r] = sacc[s][r] + cbv[s][r];
    }
    float mq[4];
    #pragma unroll
    for (int s = 0; s < 4; ++s)
      mq[s] = fmaxf(fmaxf(v[s][0], v[s][1]), fmaxf(v[s][2], v[s][3]));
    float mx = fmaxf(fmaxf(mq[0], mq[1]), fmaxf(mq[2], mq[3]));
    mx = fmaxf(mx, __shfl_xor(mx, 16));
    mx = fmaxf(mx, __shfl_xor(mx, 32));
    m_true = fmaxf(m_true, mx);

    const bool defer = (__all(mx - m_run <= 8.0f) != 0);   // wave-uniform
    float al = 1.0f;
    if (!defer){
      float mnew = fmaxf(m_run, mx);
      al = __expf(m_run - mnew);
      m_run = mnew;
    }
    float e[4][4];
    #pragma unroll
    for (int s = 0; s < 4; ++s){
      #pragma unroll
      for (int r = 0; r < 4; ++r) e[s][r] = __expf(v[s][r] - m_run);
    }
    float sq[4];
    #pragma unroll
    for (int s = 0; s < 4; ++s)
      sq[s] = (e[s][0] + e[s][1]) + (e[s][2] + e[s][3]);
    float ps = (sq[0] + sq[1]) + (sq[2] + sq[3]);
    ps += __shfl_xor(ps, 16);
    ps += __shfl_xor(ps, 32);
    l_run = l_run * al + ps;

    // P staging: row t=l15, cols n; pack bf16 pairs -> 8 ds_write_b32
    #pragma unroll
    for (int s = 0; s < 4; ++s){
      unsigned u0 = (unsigned)f2bf(e[s][0]) | ((unsigned)f2bf(e[s][1]) << 16);
      unsigned u1 = (unsigned)f2bf(e[s][2]) | ((unsigned)f2bf(e[s][3]) << 16);
      unsigned short* pr = pb + l15 * PSTR + s * 16 + quad * 4;
      *(unsigned*)(pr)     = u0;
      *(unsigned*)(pr + 2) = u1;
    }

    // o-rescale only when max actually moved (rare after warm-up)
    if (!defer){
      float aB[4];
      #pragma unroll
      for (int r = 0; r < 4; ++r) aB[r] = __shfl(al, quad*4 + r);
      #pragma unroll
      for (int dc = 0; dc < 8; ++dc){
        #pragma unroll
        for (int r = 0; r < 4; ++r) o[dc][r] *= aB[r];
      }
    }

    // wave-local LDS visibility (in-order DS per wave; just drain writes)
    asm volatile("s_waitcnt lgkmcnt(0)" ::: "memory");
    short8 pf0 = *(const short8*)(pb + l15 * PSTR + quad * 8);
    short8 pf1 = *(const short8*)(pb + l15 * PSTR + 32 + quad * 8);

    // ---- PV: O += P . sem, V frags already in regs ----
    #pragma unroll
    for (int kt = 0; kt < 2; ++kt){
      short8 pf = kt ? pf1 : pf0;
      #pragma unroll
      for (int dc = 0; dc < 8; ++dc)
        o[dc] = __builtin_amdgcn_mfma_f32_16x16x32_bf16(pf, vf[kt*8 + dc], o[dc], 0, 0, 0);
    }

    // tile boundary: K-buffer swap safety (all waves done reading buf it&1)
    __syncthreads();
  }

  // ---- epilogue: h = O/l -> out seg1 (fp32); m_true (+rowA) -> ws ----
  float rl = 1.0f / l_run;
  float rB[4];
  #pragma unroll
  for (int r = 0; r < 4; ++r) rB[r] = __shfl(rl, quad*4 + r);
  float* outB = outf + ((size_t)b * TT + t0w) * 512 + 128;
  #pragma unroll
  for (int dc = 0; dc < 8; ++dc){
    #pragma unroll
    for (int r = 0; r < 4; ++r)
      outB[(size_t)(quad*4 + r) * 512 + dc*16 + l15] = o[dc][r] * rB[r];
  }
  if (quad == 0)
    m_ws[(size_t)b * TT + t0w + l15] = m_true + rowA_part;
}

// ---------------- kernel 3a: per-chunk max of m ----------------
__global__ __launch_bounds__(256) void bw1_kernel(const float* __restrict__ m_ws,
                                                  float* __restrict__ pmax){
  __shared__ float sA[4];
  const int b = blockIdx.x >> 3, ch = blockIdx.x & 7, tid = threadIdx.x;
  float v = m_ws[(size_t)b * TT + ch * 256 + tid];
  #pragma unroll
  for (int off = 1; off < 64; off <<= 1) v = fmaxf(v, __shfl_xor(v, off));
  if ((tid & 63) == 0) sA[tid >> 6] = v;
  __syncthreads();
  if (tid == 0)
    pmax[blockIdx.x] = fmaxf(fmaxf(sA[0], sA[1]), fmaxf(sA[2], sA[3]));
}

// ---------------- kernel 3b: partial exp-sum + partial a2 ----------------
__global__ __launch_bounds__(256) void bw2_kernel(const float* __restrict__ aud,
                                                  const float* __restrict__ m_ws,
                                                  const float* __restrict__ pmax,
                                                  float* __restrict__ gpart,
                                                  float* __restrict__ part){
  __shared__ float wbuf[256];
  __shared__ float red[16 * 128];
  __shared__ float gs4[4];
  const int b = blockIdx.x >> 3, ch = blockIdx.x & 7, tid = threadIdx.x;

  float gmax = pmax[b * 8];
  #pragma unroll
  for (int i = 1; i < 8; ++i) gmax = fmaxf(gmax, pmax[b * 8 + i]);

  float w = __expf(m_ws[(size_t)b * TT + ch * 256 + tid] - gmax);
  wbuf[tid] = w;
  float sm = w;
  #pragma unroll
  for (int off = 1; off < 64; off <<= 1) sm += __shfl_xor(sm, off);
  if ((tid & 63) == 0) gs4[tid >> 6] = sm;
  __syncthreads();
  if (tid == 0) gpart[blockIdx.x] = (gs4[0] + gs4[1]) + (gs4[2] + gs4[3]);

  const int dg = tid & 15, q = tid >> 4;
  float acc[8] = {0,0,0,0,0,0,0,0};
  const float* ab = aud + ((size_t)b * TT + ch * 256 + q * 16) * DIM + dg * 8;
  for (int i = 0; i < 16; ++i){
    float av[8];
    ld8f(ab + (size_t)i * DIM, av);
    float wt = wbuf[q * 16 + i];
    #pragma unroll
    for (int j = 0; j < 8; ++j) acc[j] += wt * av[j];
  }
  #pragma unroll
  for (int j = 0; j < 8; ++j) red[q * 128 + dg * 8 + j] = acc[j];
  __syncthreads();
  if (tid < 128){
    float s = 0.f;
    #pragma unroll
    for (int q2 = 0; q2 < 16; ++q2) s += red[q2 * 128 + tid];
    part[(size_t)blockIdx.x * 128 + tid] = s;
  }
}

// ---------------- kernel 4: read seg1 (h) + bw partials, write seg0/2/3 ----------------
// bw3 fused: per block (fixed b) reduce part/gpart -> a2[128] in LDS once.
__global__ __launch_bounds__(256) void epi_kernel(const float* __restrict__ aud,
                                                  const float* __restrict__ gpart,
                                                  const float* __restrict__ part,
                                                  float* __restrict__ out){
  __shared__ float a2s[DIM];
  int id = blockIdx.x * 256 + threadIdx.x;        // BSZ*TT*16
  int c = id & 15;
  int t = (id >> 4) & (TT - 1);
  int b = id >> 15;
  size_t row = (size_t)b * TT + t;

  if (threadIdx.x < 128){
    const int d = threadIdx.x;
    float s = 0.f, g = 0.f;
    #pragma unroll
    for (int ch = 0; ch < 8; ++ch){
      s += part[(size_t)(b * 8 + ch) * 128 + d];
      g += gpart[b * 8 + ch];
    }
    a2s[d] = s / g;
  }
  __syncthreads();

  float av[8], gv[8], hv[8];
  ld8f(aud + row * DIM + c * 8, av);
  ld8f(out + row * 512 + 128 + c * 8, hv);        // h (seg1)
  #pragma unroll
  for (int j = 0; j < 8; ++j) gv[j] = a2s[c * 8 + j];

  floatx4 o0a, o0b, o2a, o2b, o3a, o3b;
  #pragma unroll
  for (int j = 0; j < 4; ++j){
    o0a[j] = av[j];           o0b[j] = av[4+j];
    o2a[j] = av[j]*hv[j];     o2b[j] = av[4+j]*hv[4+j];
    o3a[j] = av[j]*gv[j];     o3b[j] = av[4+j]*gv[4+j];
  }
  float* ob = out + row * 512 + c * 8;
  *(floatx4*)(ob)       = o0a;  *(floatx4*)(ob + 4)   = o0b;   // seg0: aud
  *(floatx4*)(ob + 256) = o2a;  *(floatx4*)(ob + 260) = o2b;   // seg2: aud*h
  *(floatx4*)(ob + 384) = o3a;  *(floatx4*)(ob + 388) = o3b;   // seg3: aud*a2
}

extern "C" void kernel_launch(void* const* d_in, const int* in_sizes, int n_in,
                              void* d_out, int out_size, void* d_ws, size_t ws_size,
                              hipStream_t stream){
  const float* aud = (const float*)d_in[0];   // fp32 inputs (verified round 4)
  const float* sem = (const float*)d_in[1];
  const float* W   = (const float*)d_in[2];
  // d_in[3] (bias) cancels in both softmaxes.
  float* out = (float*)d_out;                 // fp32 output (verified round 4)
  unsigned short* outw = (unsigned short*)d_out;

  // ws: ~329 KB
  float* ws    = (float*)d_ws;
  float* m_ws  = ws;                                   // 32768 f (128 KB)
  float* colB  = m_ws + (size_t)BSZ * TT;              // 32768 f (128 KB)
  float* a2_ws = colB + (size_t)BSZ * NSEM;            // 2048 f  (8 KB, unused now)
  float* pmax  = a2_ws + BSZ * DIM;                    // 128 f
  float* gpart = pmax + 128;                           // 128 f
  float* part  = gpart + 128;                          // 16384 f (64 KB)

  prep_kernel <<<512, 256, 0, stream>>>(sem, W, colB, outw);
  flash_kernel<<<512, 256, 0, stream>>>(aud, W, colB, m_ws, out, outw);
  bw1_kernel  <<<128, 256, 0, stream>>>(m_ws, pmax);
  bw2_kernel  <<<128, 256, 0, stream>>>(aud, m_ws, pmax, gpart, part);
  epi_kernel  <<<(BSZ * TT * 16) / 256, 256, 0, stream>>>(aud, gpart, part, out);
}